// Round 3
// baseline (356.105 us; speedup 1.0000x reference)
//
#include <hip/hip_runtime.h>
#include <cmath>

// INGP hashgrid encode, two-kernel (R3 structure).
//   Gather: level pinned per XCD (blockIdx%8; phase2 lvl=15-k) -> XCD's 4MiB
//   L2 holds its level's table.
//   Model history: R6 (points->LDS) NULL, R7 (2x2x2-blocked dense, fewer
//   distinct lines, same instruction count) NULL => bound is VMEM REQUEST
//   ISSUE/PROCESSING throughput (per instruction x line-within-instruction),
//   NOT distinct-line misses. ~50M gather requests <-> 203us.
//   R8 therefore reduces issued requests:
//   - levels 0-4: z-halo dense tables dense[x][y][z] = {v(z),v(z+1)} (16B),
//     stored in d_out (5.5MB << 64MB; transpose overwrites after gather).
//     Exactly 4 uniform vf4 loads per point-level, no parity divergence.
//   - levels 5-15: uniform vf4 at (b0&~1) covers even-ix x-pair AND odd-ix
//     x=0 corner (select by b0&1); masked 4x float2 fixup for odd lanes only.
//     Divergent waves: 12 -> 8 issued VMEM instructions.
//   - points staged as vf4 (2 instr vs 6).
//   R5 lesson: cross-XCD partial-line output stores are catastrophic ->
//   keep level-major ws + LDS-tile transpose.

constexpr int LVLS = 16;
constexpr int NDENSE = 5;            // levels 0..4 dense (r=16,22,30,42,58)
constexpr unsigned TBL = 1u << 19;
constexpr unsigned TMASK = TBL - 1u;
constexpr unsigned P1 = 2654435761u;
constexpr unsigned P2 = 805459861u;
constexpr int PTS_PER_BLOCK = 512;   // 256 threads x 2 points

typedef float vf2 __attribute__((ext_vector_type(2)));
typedef float vf4 __attribute__((ext_vector_type(4)));

struct LvlCfg {
    float r[LVLS];
    int doff[LVLS];   // dense entry offset (float4 units); levels 0..NDENSE-1
    int dZ[LVLS];     // Z = r+1   (z-base coord range 0..r)
    int dXZ[LVLS];    // X*Z, X = r+2 (coord range 0..r+1)
};

// dense[doff[l] + (x*X + y)*Z + z] = { tab[h(x,y,z)], tab[h(x,y,z+1)] }  (16B)
__global__ __launch_bounds__(256) void ingp_prep(
    const float* __restrict__ tables, vf4* __restrict__ dense,
    LvlCfg cfg, int total)
{
    int i = blockIdx.x * 256 + threadIdx.x;
    if (i >= total) return;
    int l = 0;
    #pragma unroll
    for (int k = 1; k < NDENSE; ++k) if (i >= cfg.doff[k]) l = k;
    int e = i - cfg.doff[l];
    int Z = cfg.dZ[l];
    int X = cfg.dXZ[l] / Z;
    int z = e % Z; int t2 = e / Z;
    int y = t2 % X; int x = t2 / X;
    unsigned hy = (unsigned)y * P1;
    unsigned hz = (unsigned)z * P2;
    unsigned h0 = ((unsigned)x ^ hy ^ hz) & TMASK;
    unsigned h1 = ((unsigned)x ^ hy ^ (hz + P2)) & TMASK;
    const float2* tab = (const float2*)tables + (size_t)l * TBL;
    float2 a = tab[h0], b = tab[h1];
    vf4 o; o.x = a.x; o.y = a.y; o.z = b.x; o.w = b.y;
    __builtin_nontemporal_store(o, dense + i);
}

template<bool USE_WS>
__global__ __launch_bounds__(256) void ingp_gather(
    const float* __restrict__ pts,
    const float* __restrict__ tables,
    const vf4* __restrict__ dense,
    float2* __restrict__ dst,     // USE_WS: [L][N] float2 ; else [N][L] float2
    LvlCfg cfg, int npts, int bpl, int ndense)
{
    __shared__ float s_res[LVLS];
    __shared__ int s_doff[LVLS], s_dZ[LVLS], s_dXZ[LVLS];
    __shared__ float s_pts[PTS_PER_BLOCK * 3];
    if (threadIdx.x < LVLS) {
        s_res[threadIdx.x]  = cfg.r[threadIdx.x];
        s_doff[threadIdx.x] = cfg.doff[threadIdx.x];
        s_dZ[threadIdx.x]   = cfg.dZ[threadIdx.x];
        s_dXZ[threadIdx.x]  = cfg.dXZ[threadIdx.x];
    }

    int b = blockIdx.x;
    int phase_blocks = 8 * bpl;
    int xcd = b & 7;
    int phase = b / phase_blocks;
    int lvl = phase == 0 ? xcd : 15 - xcd;   // balanced pairing (k, 15-k)
    int q = (b % phase_blocks) >> 3;
    int t = threadIdx.x;

    // Stage this block's 512 points into LDS. Full blocks: 2 vf4 instrs
    // (384 16B lane-loads); tail block: scalar dword fallback.
    {
        int base_dw = q * PTS_PER_BLOCK * 3;
        int total_dw = npts * 3 - base_dw;   // >0 for every launched block
        const float* src = pts + base_dw;
        if (total_dw >= PTS_PER_BLOCK * 3) {
            const vf4* src4 = (const vf4*)src;   // 6144B-multiple offset
            #pragma unroll
            for (int k = 0; k < 2; ++k) {
                int i4 = t + k * 256;
                if (i4 < PTS_PER_BLOCK * 3 / 4) {
                    vf4 v = __builtin_nontemporal_load(src4 + i4);
                    *(vf4*)(s_pts + i4 * 4) = v;
                }
            }
        } else {
            #pragma unroll
            for (int k = 0; k < 6; ++k) {
                int i = t + k * 256;
                float v = 0.f;
                if (i < total_dw) v = __builtin_nontemporal_load(src + i);
                s_pts[i] = v;
            }
        }
    }
    __syncthreads();

    float r = s_res[lvl];
    bool dense_lvl = lvl < ndense;
    const float2* __restrict__ tab = (const float2*)tables + (size_t)lvl * TBL;
    const vf4* __restrict__ dtab = dense_lvl ? dense + s_doff[lvl] : (const vf4*)tab;
    unsigned Z  = dense_lvl ? (unsigned)s_dZ[lvl]  : 1u;
    unsigned XZ = dense_lvl ? (unsigned)s_dXZ[lvl] : 1u;

    int p0 = q * PTS_PER_BLOCK + t;

    #pragma unroll
    for (int s = 0; s < 2; ++s) {
        int lp = t + s * 256;          // local point index in LDS
        int pglob = p0 + s * 256;      // global point index
        bool valid = pglob < npts;
        float px = s_pts[lp * 3 + 0];
        float py = s_pts[lp * 3 + 1];
        float pz = s_pts[lp * 3 + 2];
        float x = (px + 1.0f) * 0.5f;
        float y = (py + 1.0f) * 0.5f;
        float z = (pz + 1.0f) * 0.5f;
        float posx = x * r, posy = y * r, posz = z * r;
        float fx = floorf(posx), fy = floorf(posy), fz = floorf(posz);
        float wx = posx - fx, wy = posy - fy, wz = posz - fz;
        unsigned ix = (unsigned)fx, iy = (unsigned)fy, iz = (unsigned)fz;

        // v[i*4 + j*2 + k]: corner (i,j,k)
        float2 v[8];

        if (dense_lvl) {
            // z-halo dense: entry (x,y,z) = {val(z), val(z+1)}; 4 uniform vf4.
            unsigned e00 = ix * XZ + iy * Z + iz;
            vf4 q00 = dtab[e00];
            vf4 q01 = dtab[e00 + Z];
            vf4 q10 = dtab[e00 + XZ];
            vf4 q11 = dtab[e00 + XZ + Z];
            v[0] = make_float2(q00.x, q00.y); v[1] = make_float2(q00.z, q00.w);
            v[2] = make_float2(q01.x, q01.y); v[3] = make_float2(q01.z, q01.w);
            v[4] = make_float2(q10.x, q10.y); v[5] = make_float2(q10.z, q10.w);
            v[6] = make_float2(q11.x, q11.y); v[7] = make_float2(q11.z, q11.w);
        } else {
            unsigned hy0 = iy * P1;
            unsigned hz0 = iz * P2;
            unsigned hyz[4];
            hyz[0] = hy0 ^ hz0;
            hyz[1] = hy0 ^ (hz0 + P2);
            hyz[2] = (hy0 + P1) ^ hz0;
            hyz[3] = (hy0 + P1) ^ (hz0 + P2);

            // Uniform part: vf4 at (b0&~1) = {tab[b0&~1], tab[b0|1]}.
            //  - ix even: covers BOTH x-corners (b1 = b0^1).
            //  - ix odd : covers x=0 corner (select by b0&1); x=1 fixed below.
            #pragma unroll
            for (int yz = 0; yz < 4; ++yz) {
                unsigned b0 = (ix ^ hyz[yz]) & TMASK;
                vf4 qd = *(const vf4*)(tab + (b0 & ~1u));
                float2 lo = make_float2(qd.x, qd.y);
                float2 hi = make_float2(qd.z, qd.w);
                bool odd = (b0 & 1u) != 0u;
                v[yz]     = odd ? hi : lo;
                v[4 + yz] = odd ? lo : hi;   // correct only when ix even
            }
            if (ix & 1u) {                    // masked fixup, odd-ix lanes
                #pragma unroll
                for (int yz = 0; yz < 4; ++yz)
                    v[4 + yz] = tab[((ix + 1u) ^ hyz[yz]) & TMASK];
            }
        }

        float ox = 1.0f - wx, oy = 1.0f - wy, oz = 1.0f - wz;
        float w[8];
        w[0] = (ox * oy) * oz;   // (0,0,0)
        w[1] = (ox * oy) * wz;   // (0,0,1)
        w[2] = (ox * wy) * oz;   // (0,1,0)
        w[3] = (ox * wy) * wz;   // (0,1,1)
        w[4] = (wx * oy) * oz;   // (1,0,0)
        w[5] = (wx * oy) * wz;   // (1,0,1)
        w[6] = (wx * wy) * oz;   // (1,1,0)
        w[7] = (wx * wy) * wz;   // (1,1,1)

        float f0 = w[0] * v[0].x;
        float f1 = w[0] * v[0].y;
        #pragma unroll
        for (int c = 1; c < 8; ++c) {
            f0 += w[c] * v[c].x;
            f1 += w[c] * v[c].y;
        }
        if (valid) {
            vf2 o; o.x = f0; o.y = f1;
            if (USE_WS)
                __builtin_nontemporal_store(o, (vf2*)(dst + (size_t)lvl * npts + pglob));
            else
                dst[(size_t)pglob * LVLS + lvl] = make_float2(f0, f1);
        }
    }
}

// ws [L][N] float2  ->  out [N][L] float2, all-coalesced via LDS tile.
__global__ __launch_bounds__(256) void ingp_transpose(
    const float2* __restrict__ ws, float4* __restrict__ out, int npts)
{
    __shared__ float2 a[LVLS][258];
    int base = blockIdx.x * 256;
    int t = threadIdx.x;

    #pragma unroll
    for (int l = 0; l < LVLS; ++l) {
        int pp = base + t;
        float2 val = make_float2(0.f, 0.f);
        if (pp < npts) {
            vf2 v = __builtin_nontemporal_load((const vf2*)(ws + (size_t)l * npts + pp));
            val = make_float2(v.x, v.y);
        }
        a[l][t] = val;
    }
    __syncthreads();

    int j = t & 7;
    int pl = t >> 3;
    #pragma unroll
    for (int it = 0; it < 8; ++it) {
        int pt = pl + it * 32;
        if (base + pt < npts) {
            float2 u = a[2 * j][pt];
            float2 v = a[2 * j + 1][pt];
            vf4 o; o.x = u.x; o.y = u.y; o.z = v.x; o.w = v.y;
            __builtin_nontemporal_store(o, (vf4*)(out + (size_t)(base + pt) * 8 + j));
        }
    }
}

extern "C" void kernel_launch(void* const* d_in, const int* in_sizes, int n_in,
                              void* d_out, int out_size, void* d_ws, size_t ws_size,
                              hipStream_t stream) {
    const float* pts    = (const float*)d_in[0];
    const float* tables = (const float*)d_in[1];
    int npts = in_sizes[0] / 3;

    // numpy-bitwise RES: GROWTH = exp((log(2048)-log(16))/15); floor(16*G**l)
    LvlCfg cfg;
    double growth = exp((log(2048.0) - log(16.0)) / 15.0);
    int cum = 0;
    for (int l = 0; l < LVLS; ++l) {
        cfg.r[l] = (float)floor(16.0 * pow(growth, (double)l));
        cfg.doff[l] = 0; cfg.dZ[l] = 1; cfg.dXZ[l] = 1;
        if (l < NDENSE) {
            int R = (int)cfg.r[l];
            int X = R + 2;                 // coords 0..r+1
            int Z = R + 1;                 // z-base 0..r (pos<=r incl. tie)
            cfg.doff[l] = cum;
            cfg.dZ[l] = Z; cfg.dXZ[l] = X * Z;
            cum += X * X * Z;              // float4 entries this level
        }
    }
    size_t dense_bytes = (size_t)cum * 16;

    int bpl = (npts + PTS_PER_BLOCK - 1) / PTS_PER_BLOCK;
    int grid = LVLS * bpl;

    size_t ws_needed = (size_t)LVLS * npts * sizeof(float2);
    bool use_ws = ws_size >= ws_needed;
    // Dense tables live in d_out (transpose rewrites every byte afterwards).
    // Only valid with the ws+transpose path (else gather writes d_out itself).
    bool use_dense = use_ws && ((size_t)out_size >= dense_bytes);

    vf4* dense = use_dense ? (vf4*)d_out : nullptr;
    int ndense = use_dense ? NDENSE : 0;

    if (use_dense) {
        int pgrid = (cum + 255) / 256;
        hipLaunchKernelGGL(ingp_prep, dim3(pgrid), dim3(256), 0, stream,
                           tables, dense, cfg, cum);
    }

    if (use_ws) {
        float2* ws = (float2*)d_ws;
        hipLaunchKernelGGL(ingp_gather<true>, dim3(grid), dim3(256), 0, stream,
                           pts, tables, dense, ws, cfg, npts, bpl, ndense);
        hipLaunchKernelGGL(ingp_transpose, dim3((npts + 255) / 256), dim3(256), 0, stream,
                           ws, (float4*)d_out, npts);
    } else {
        hipLaunchKernelGGL(ingp_gather<false>, dim3(grid), dim3(256), 0, stream,
                           pts, tables, dense, (float2*)d_out, cfg, npts, bpl, ndense);
    }
}

// Round 4
// 324.883 us; speedup vs baseline: 1.0961x; 1.0961x over previous
//
#include <hip/hip_runtime.h>
#include <cmath>

// INGP hashgrid encode.
//   Model history: gather is bound by random L2 line-lookups (~50M: 16 lvls x
//   524K pts x ~6) at ~31G/s per XCD-L2 => ~203us. R6 (fewer point lines),
//   R7 (fewer distinct lines), R8 (fewer VMEM instructions) all null/worse =>
//   lookup count with ZERO wave-level sharing is the invariant cost.
//   R9: Morton-bin sort (32^3 bins) => lanes of a wave are spatially adjacent
//   => TA merges same-line corner lookups + L1 hits on coarse/mid levels.
//   Schedule rebalanced for post-sort costs: fine levels 8-15 XCD-pinned
//   (phase 0, table-resident in that XCD's 4MiB L2); coarse 0-7 unpinned
//   round-robin (phase 1) since their sorted per-block footprints are tiny.
//   Output order restored in transpose via sort permutation; out rows are
//   128B-aligned full-line scatters (R5 lesson: partial-line cross-XCD
//   scatter is catastrophic; full 2-line rows are fine).

constexpr int LVLS = 16;
constexpr unsigned TBL = 1u << 19;
constexpr unsigned TMASK = TBL - 1u;
constexpr unsigned P1 = 2654435761u;
constexpr unsigned P2 = 805459861u;
constexpr int PTS_PER_BLOCK = 512;   // 256 threads x 2 points
constexpr int NBINS = 32768;         // 32^3 Morton bins

typedef float vf2 __attribute__((ext_vector_type(2)));
typedef float vf4 __attribute__((ext_vector_type(4)));

struct ResArr { float r[LVLS]; };

__device__ __forceinline__ unsigned spread5(unsigned v) {
    v &= 31u;
    v = (v | (v << 8)) & 0x100Fu;
    v = (v | (v << 4)) & 0x10C3u;
    v = (v | (v << 2)) & 0x1249u;
    return v;
}

__device__ __forceinline__ unsigned bin_key(float px, float py, float pz) {
    float x = (px + 1.0f) * 0.5f;
    float y = (py + 1.0f) * 0.5f;
    float z = (pz + 1.0f) * 0.5f;
    unsigned bx = (unsigned)fminf(31.f, fmaxf(0.f, floorf(x * 32.f)));
    unsigned by = (unsigned)fminf(31.f, fmaxf(0.f, floorf(y * 32.f)));
    unsigned bz = (unsigned)fminf(31.f, fmaxf(0.f, floorf(z * 32.f)));
    return spread5(bx) | (spread5(by) << 1) | (spread5(bz) << 2);
}

__global__ __launch_bounds__(256) void ingp_hist(
    const float* __restrict__ pts, unsigned* __restrict__ hist, int npts)
{
    int i = blockIdx.x * 256 + threadIdx.x;
    if (i >= npts) return;
    float px = pts[i * 3 + 0], py = pts[i * 3 + 1], pz = pts[i * 3 + 2];
    atomicAdd(&hist[bin_key(px, py, pz)], 1u);
}

// Exclusive scan of 32768 bin counts, single block of 1024 threads.
__global__ __launch_bounds__(1024) void ingp_scan(
    const unsigned* __restrict__ hist, unsigned* __restrict__ offs)
{
    __shared__ unsigned sc[1024];
    int t = threadIdx.x;
    unsigned loc[32];
    unsigned s = 0;
    #pragma unroll
    for (int i = 0; i < 32; ++i) { loc[i] = s; s += hist[t * 32 + i]; }
    sc[t] = s;
    __syncthreads();
    for (int d = 1; d < 1024; d <<= 1) {
        unsigned v = (t >= d) ? sc[t - d] : 0u;
        __syncthreads();
        sc[t] += v;
        __syncthreads();
    }
    unsigned base = sc[t] - s;   // exclusive prefix of this thread's chunk
    #pragma unroll
    for (int i = 0; i < 32; ++i) offs[t * 32 + i] = base + loc[i];
}

__global__ __launch_bounds__(256) void ingp_scatter(
    const float* __restrict__ pts, unsigned* __restrict__ offs,
    float* __restrict__ pts_s, int* __restrict__ perm, int npts)
{
    int i = blockIdx.x * 256 + threadIdx.x;
    if (i >= npts) return;
    float px = pts[i * 3 + 0], py = pts[i * 3 + 1], pz = pts[i * 3 + 2];
    unsigned pos = atomicAdd(&offs[bin_key(px, py, pz)], 1u);
    pts_s[pos * 3 + 0] = px;
    pts_s[pos * 3 + 1] = py;
    pts_s[pos * 3 + 2] = pz;
    perm[pos] = i;
}

template<bool USE_WS>
__global__ __launch_bounds__(256) void ingp_gather(
    const float* __restrict__ pts,    // sorted (or raw on fallback)
    const float* __restrict__ tables,
    float2* __restrict__ dst,     // USE_WS: [L][N] float2 ; else [N][L] float2
    ResArr ra, int npts, int bpl)
{
    __shared__ float s_res[LVLS];
    __shared__ float s_pts[PTS_PER_BLOCK * 3];
    if (threadIdx.x < LVLS) s_res[threadIdx.x] = ra.r[threadIdx.x];

    // Schedule: phase 0 (blocks [0, 8*bpl)): fine level 8+xcd, XCD-pinned.
    //           phase 1: coarse levels 0..7, unpinned, bpl blocks each.
    int b = blockIdx.x;
    int lvl, q;
    if (b < 8 * bpl) { lvl = 8 + (b & 7); q = b >> 3; }
    else { int u = b - 8 * bpl; lvl = u / bpl; q = u - lvl * bpl; }
    int t = threadIdx.x;

    // Stage this block's 512 points into LDS (vf4 for full blocks).
    {
        int base_dw = q * PTS_PER_BLOCK * 3;
        int total_dw = npts * 3 - base_dw;   // >0 for every launched block
        const float* src = pts + base_dw;
        if (total_dw >= PTS_PER_BLOCK * 3) {
            const vf4* src4 = (const vf4*)src;   // 6144B-multiple offset
            #pragma unroll
            for (int k = 0; k < 2; ++k) {
                int i4 = t + k * 256;
                if (i4 < PTS_PER_BLOCK * 3 / 4) {
                    vf4 v = __builtin_nontemporal_load(src4 + i4);
                    *(vf4*)(s_pts + i4 * 4) = v;
                }
            }
        } else {
            #pragma unroll
            for (int k = 0; k < 6; ++k) {
                int i = t + k * 256;
                float v = 0.f;
                if (i < total_dw) v = __builtin_nontemporal_load(src + i);
                s_pts[i] = v;
            }
        }
    }
    __syncthreads();

    float r = s_res[lvl];
    const float2* __restrict__ tab = (const float2*)tables + (size_t)lvl * TBL;

    int p0 = q * PTS_PER_BLOCK + t;

    #pragma unroll
    for (int s = 0; s < 2; ++s) {
        int lp = t + s * 256;          // local point index in LDS
        int pglob = p0 + s * 256;      // global (sorted) point index
        bool valid = pglob < npts;
        float px = s_pts[lp * 3 + 0];
        float py = s_pts[lp * 3 + 1];
        float pz = s_pts[lp * 3 + 2];
        float x = (px + 1.0f) * 0.5f;
        float y = (py + 1.0f) * 0.5f;
        float z = (pz + 1.0f) * 0.5f;
        float posx = x * r, posy = y * r, posz = z * r;
        float fx = floorf(posx), fy = floorf(posy), fz = floorf(posz);
        float wx = posx - fx, wy = posy - fy, wz = posz - fz;
        unsigned ix = (unsigned)fx, iy = (unsigned)fy, iz = (unsigned)fz;
        unsigned hx0 = ix,      hx1 = ix + 1u;
        unsigned hy0 = iy * P1;
        unsigned hz0 = iz * P2, hz1 = hz0 + P2;

        // yz-combination hashes (j,k): yz = j*2+k
        unsigned hyz[4];
        hyz[0] = hy0 ^ hz0;
        hyz[1] = hy0 ^ hz1;
        hyz[2] = (hy0 + P1) ^ hz0;
        hyz[3] = (hy0 + P1) ^ hz1;

        // v[i*4+yz]: corner (i,j,k)
        float2 v[8];
        if ((ix & 1u) == 0u) {
            // x-pair idx differ by ^1 -> one aligned float4 covers both.
            #pragma unroll
            for (int yz = 0; yz < 4; ++yz) {
                unsigned b0 = (hx0 ^ hyz[yz]) & TMASK;   // x=0 corner
                const vf4* lp4 = (const vf4*)(tab + (b0 & ~1u));
                vf4 qd = *lp4;
                float2 lo = make_float2(qd.x, qd.y);
                float2 hi = make_float2(qd.z, qd.w);
                bool odd = (b0 & 1u) != 0u;
                v[yz]     = odd ? hi : lo;   // x=0 corner
                v[4 + yz] = odd ? lo : hi;   // x=1 corner (idx = b0^1)
            }
        } else {
            #pragma unroll
            for (int yz = 0; yz < 4; ++yz) {
                unsigned b0 = (hx0 ^ hyz[yz]) & TMASK;
                unsigned b1 = (hx1 ^ hyz[yz]) & TMASK;
                v[yz]     = tab[b0];
                v[4 + yz] = tab[b1];
            }
        }

        float ox = 1.0f - wx, oy = 1.0f - wy, oz = 1.0f - wz;
        float w[8];
        w[0] = (ox * oy) * oz;   // (0,0,0)
        w[1] = (ox * oy) * wz;   // (0,0,1)
        w[2] = (ox * wy) * oz;   // (0,1,0)
        w[3] = (ox * wy) * wz;   // (0,1,1)
        w[4] = (wx * oy) * oz;   // (1,0,0)
        w[5] = (wx * oy) * wz;   // (1,0,1)
        w[6] = (wx * wy) * oz;   // (1,1,0)
        w[7] = (wx * wy) * wz;   // (1,1,1)

        float f0 = w[0] * v[0].x;
        float f1 = w[0] * v[0].y;
        #pragma unroll
        for (int c = 1; c < 8; ++c) {
            f0 += w[c] * v[c].x;
            f1 += w[c] * v[c].y;
        }
        if (valid) {
            vf2 o; o.x = f0; o.y = f1;
            if (USE_WS)
                __builtin_nontemporal_store(o, (vf2*)(dst + (size_t)lvl * npts + pglob));
            else
                dst[(size_t)pglob * LVLS + lvl] = make_float2(f0, f1);
        }
    }
}

// ws [L][N_sorted] float2 -> out [N_orig][L] float2 via perm (LDS tile).
// perm == nullptr -> identity (unsorted fallback).
__global__ __launch_bounds__(256) void ingp_transpose(
    const float2* __restrict__ ws, const int* __restrict__ perm,
    float4* __restrict__ out, int npts)
{
    __shared__ float2 a[LVLS][258];
    __shared__ int s_perm[256];
    int base = blockIdx.x * 256;
    int t = threadIdx.x;

    if (base + t < npts) s_perm[t] = perm ? perm[base + t] : base + t;

    #pragma unroll
    for (int l = 0; l < LVLS; ++l) {
        int pp = base + t;
        float2 val = make_float2(0.f, 0.f);
        if (pp < npts) {
            vf2 v = __builtin_nontemporal_load((const vf2*)(ws + (size_t)l * npts + pp));
            val = make_float2(v.x, v.y);
        }
        a[l][t] = val;
    }
    __syncthreads();

    int j = t & 7;
    int pl = t >> 3;
    #pragma unroll
    for (int it = 0; it < 8; ++it) {
        int pt = pl + it * 32;
        if (base + pt < npts) {
            int orig = s_perm[pt];
            float2 u = a[2 * j][pt];
            float2 v = a[2 * j + 1][pt];
            vf4 o; o.x = u.x; o.y = u.y; o.z = v.x; o.w = v.y;
            // row = 128B aligned; 8 lanes cover 2 full lines contiguously.
            __builtin_nontemporal_store(o, (vf4*)(out + (size_t)orig * 8 + j));
        }
    }
}

extern "C" void kernel_launch(void* const* d_in, const int* in_sizes, int n_in,
                              void* d_out, int out_size, void* d_ws, size_t ws_size,
                              hipStream_t stream) {
    const float* pts    = (const float*)d_in[0];
    const float* tables = (const float*)d_in[1];
    int npts = in_sizes[0] / 3;

    // numpy-bitwise RES: GROWTH = exp((log(2048)-log(16))/15); floor(16*G**l)
    ResArr ra;
    double growth = exp((log(2048.0) - log(16.0)) / 15.0);
    for (int l = 0; l < LVLS; ++l)
        ra.r[l] = (float)floor(16.0 * pow(growth, (double)l));

    int bpl = (npts + PTS_PER_BLOCK - 1) / PTS_PER_BLOCK;
    int grid = LVLS * bpl;

    // Workspace layout: [ws: L*N float2][perm: N int][hist: NBINS u32][offs: NBINS u32]
    size_t ws_needed = (size_t)LVLS * npts * sizeof(float2);
    size_t sort_extra = (size_t)npts * sizeof(int) + 2ull * NBINS * sizeof(unsigned);
    bool use_ws = ws_size >= ws_needed;
    bool use_sort = use_ws && (ws_size >= ws_needed + sort_extra)
                           && ((size_t)out_size >= (size_t)npts * 3 * sizeof(float));

    int pgrid = (npts + 255) / 256;

    if (use_sort) {
        float2*  ws    = (float2*)d_ws;
        int*     perm  = (int*)((char*)d_ws + ws_needed);
        unsigned* hist = (unsigned*)(perm + npts);
        unsigned* offs = hist + NBINS;
        float*   pts_s = (float*)d_out;   // scratch; transpose overwrites later

        hipMemsetAsync(hist, 0, NBINS * sizeof(unsigned), stream);
        hipLaunchKernelGGL(ingp_hist, dim3(pgrid), dim3(256), 0, stream,
                           pts, hist, npts);
        hipLaunchKernelGGL(ingp_scan, dim3(1), dim3(1024), 0, stream,
                           hist, offs);
        hipLaunchKernelGGL(ingp_scatter, dim3(pgrid), dim3(256), 0, stream,
                           pts, offs, pts_s, perm, npts);
        hipLaunchKernelGGL(ingp_gather<true>, dim3(grid), dim3(256), 0, stream,
                           pts_s, tables, ws, ra, npts, bpl);
        hipLaunchKernelGGL(ingp_transpose, dim3(pgrid), dim3(256), 0, stream,
                           ws, perm, (float4*)d_out, npts);
    } else if (use_ws) {
        float2* ws = (float2*)d_ws;
        hipLaunchKernelGGL(ingp_gather<true>, dim3(grid), dim3(256), 0, stream,
                           pts, tables, ws, ra, npts, bpl);
        hipLaunchKernelGGL(ingp_transpose, dim3(pgrid), dim3(256), 0, stream,
                           ws, (const int*)nullptr, (float4*)d_out, npts);
    } else {
        hipLaunchKernelGGL(ingp_gather<false>, dim3(grid), dim3(256), 0, stream,
                           pts, tables, (float2*)d_out, ra, npts, bpl);
    }
}